// Round 12
// baseline (101.686 us; speedup 1.0000x reference)
//
#include <hip/hip_runtime.h>
#include <hip/hip_bf16.h>

#define B_ 4
#define T_ 128
#define U_ 64
#define D_ 512
#define H_ 640
#define V_ 1024

typedef float f32x4 __attribute__((ext_vector_type(4)));

union U2L { uint2 u; long long l; };
union U4L2 { uint4 u; long long l[2]; };

// ---------------------------------------------------------------------------
// P0 fused prep (one launch):
//  blocks 0..191  : proj  ps = SRC@W1[:D] (512x640); pt = TGT@W1[D:]+b1
//  blocks 192..271: pack  W2 -> fp8 e4m3 fragment cells, column-permuted
//    (frag (kq,wid,nf,l16) holds original col wid*64 + l16*4 + nf).
//    uint2 cell at [kq*1024 + wid*64 + (nf>>1)*32 + l16*2 + (nf&1)].
// ---------------------------------------------------------------------------
__global__ __launch_bounds__(640) void k_prep(
    const float* __restrict__ W2, uint2* __restrict__ w2p8,
    const int* __restrict__ slen, const int* __restrict__ tlen,
    float* __restrict__ out_tail,
    const float* __restrict__ src, const float* __restrict__ tgt,
    const float* __restrict__ W1, const float* __restrict__ b1,
    float* __restrict__ ps, float* __restrict__ pt) {
  __shared__ __align__(16) float lin[D_ * 4];
  int bid = blockIdx.x, tid = threadIdx.x;
  if (bid < 192) {
    bool is_t = bid >= 128;
    const float* in; const float* w; float* outp;
    if (!is_t) {
      int r0 = bid * 4;
      in = src + (size_t)r0 * D_; w = W1; outp = ps + (size_t)r0 * H_;
    } else {
      int r0 = (bid - 128) * 4;
      in = tgt + (size_t)r0 * D_; w = W1 + (size_t)D_ * H_; outp = pt + (size_t)r0 * H_;
    }
    for (int idx = tid; idx < 4 * D_; idx += 640) {
      int r = idx >> 9, k = idx & (D_ - 1);
      lin[k * 4 + r] = in[idx];
    }
    __syncthreads();
    float a0 = 0.f, a1 = 0.f, a2 = 0.f, a3 = 0.f;
    int j = tid;
    for (int k = 0; k < D_; ++k) {
      float wv = w[(size_t)k * H_ + j];
      f32x4 x = *(const f32x4*)&lin[k * 4];
      a0 += x[0] * wv; a1 += x[1] * wv; a2 += x[2] * wv; a3 += x[3] * wv;
    }
    float bb = is_t ? b1[j] : 0.f;
    outp[0 * H_ + j] = a0 + bb;
    outp[1 * H_ + j] = a1 + bb;
    outp[2 * H_ + j] = a2 + bb;
    outp[3 * H_ + j] = a3 + bb;
  } else {
    int kq = bid - 192;            // 0..79
    for (int idx = tid; idx < V_; idx += 640) {
      int wid = idx >> 6, rem = idx & 63, nf = rem >> 4, l16 = rem & 15;
      int col = wid * 64 + l16 * 4 + nf;
      float f[8];
      #pragma unroll
      for (int j = 0; j < 8; ++j) f[j] = W2[(size_t)(kq * 8 + j) * V_ + col];
      int d0 = __builtin_amdgcn_cvt_pk_fp8_f32(f[0], f[1], 0, 0);
      d0 = __builtin_amdgcn_cvt_pk_fp8_f32(f[2], f[3], d0, 1);
      int d1 = __builtin_amdgcn_cvt_pk_fp8_f32(f[4], f[5], 0, 0);
      d1 = __builtin_amdgcn_cvt_pk_fp8_f32(f[6], f[7], d1, 1);
      uint2 c; c.x = (unsigned)d0; c.y = (unsigned)d1;
      w2p8[(size_t)kq * 1024 + wid * 64 + (nf >> 1) * 32 + l16 * 2 + (nf & 1)] = c;
    }
    if (bid == 192 && tid < 8)
      out_tail[tid] = (tid < 4) ? (float)slen[tid] : (float)tlen[tid - 4];
  }
}

// ---------------------------------------------------------------------------
// PHASE-SPLIT DIAGNOSTIC (R12): gen moved out of k_joint into k_genA, which
// materializes A = tanh(ps+pt) as fp8 uint2 cells in workspace:
//   a8[bid*5120 + m*80 + kq], bid = the SAME (b,t) mapping as k_joint2 so
// the A-tile lands in (and is read back from) the producer XCD's L2.
// Thread (gm=tid>>4, gk=tid&15) writes cells kq=i*16+gk: 128B-contiguous
// per 16-lane group.
// ---------------------------------------------------------------------------
__global__ __launch_bounds__(1024, 2) void k_genA(
    const float* __restrict__ ps, const float* __restrict__ pt,
    uint2* __restrict__ a8) {
  int bid = blockIdx.x;                    // 0..511
  int xcd = bid & 7;
  int b = xcd >> 1;
  int t = (bid >> 3) + (xcd & 1) * 64;
  int tid = threadIdx.x;
  int gm = tid >> 4, gk = tid & 15;
  const float* psrow = ps + (size_t)(b * T_ + t) * H_;
  const float* ptrow = pt + (size_t)(b * U_ + gm) * H_;
  uint2* arow = a8 + (size_t)bid * 5120 + gm * 80;
  #pragma unroll
  for (int i = 0; i < 5; ++i) {
    int kq = i * 16 + gk;
    const float4* pp = (const float4*)(psrow + kq * 8);
    const float4* qq = (const float4*)(ptrow + kq * 8);
    float4 p0 = pp[0], p1 = pp[1];
    float4 q0 = qq[0], q1 = qq[1];
    float x[8] = {p0.x + q0.x, p0.y + q0.y, p0.z + q0.z, p0.w + q0.w,
                  p1.x + q1.x, p1.y + q1.y, p1.z + q1.z, p1.w + q1.w};
    float h[8];
    #pragma unroll
    for (int j = 0; j < 8; ++j) {
      float e = __expf(2.f * x[j]);
      h[j] = 1.f - 2.f * __builtin_amdgcn_rcpf(e + 1.f);
    }
    int d0 = __builtin_amdgcn_cvt_pk_fp8_f32(h[0], h[1], 0, 0);
    d0 = __builtin_amdgcn_cvt_pk_fp8_f32(h[2], h[3], d0, 1);
    int d1 = __builtin_amdgcn_cvt_pk_fp8_f32(h[4], h[5], 0, 0);
    d1 = __builtin_amdgcn_cvt_pk_fp8_f32(h[6], h[7], d1, 1);
    uint2 c; c.x = (unsigned)d0; c.y = (unsigned)d1;
    arow[kq] = c;
  }
}

// ---------------------------------------------------------------------------
// Main (R11 minus gen): stage A-tile from ws into the SAME LDS layout
// [m*81+kq] (5 uint2 loads + ds_write per thread), then byte-identical fp8
// K-loop and epilogue. rocprof now reports the gen phase (k_genA) and the
// K+softmax phase (k_joint2) separately -- the subtraction R11 couldn't do.
// ---------------------------------------------------------------------------
__global__ __launch_bounds__(1024, 4) void k_joint2(
    const uint2* __restrict__ a8,
    const uint2* __restrict__ w2p8, const float* __restrict__ b2,
    float* __restrict__ out) {
  __shared__ uint2 ldsA[64 * 81];          // 41.5 KiB, [m][kq] padded rows
  __shared__ float red[16][64][2];         // 8 KiB
  __shared__ float lzs[64];
  int bid = blockIdx.x;                    // 0..511
  int xcd = bid & 7;
  int b = xcd >> 1;
  int t = (bid >> 3) + (xcd & 1) * 64;
  int tid = threadIdx.x;
  int lane = tid & 63, wid = tid >> 6;     // wid 0..15
  int l16 = lane & 15, lg = lane >> 4;

  // ---- phase 1': stage A-tile (L2 -> LDS), same mapping as k_genA ----
  {
    int gm = tid >> 4, gk = tid & 15;
    const uint2* asrc = a8 + (size_t)bid * 5120 + gm * 80;
    uint2* wrow = &ldsA[gm * 81];
    #pragma unroll
    for (int i = 0; i < 5; ++i) {
      int kq = i * 16 + gk;
      wrow[kq] = asrc[kq];
    }
  }
  __syncthreads();

  f32x4 acc[4][4];
  #pragma unroll
  for (int mf = 0; mf < 4; ++mf)
    #pragma unroll
    for (int nf = 0; nf < 4; ++nf) {
      f32x4 z = {0.f, 0.f, 0.f, 0.f};
      acc[mf][nf] = z;
    }

  // ---- phase 2: K loop (20 iters of K=32), fp8 MFMA (byte-identical R11) --
  {
    const uint2* arow = ldsA + l16 * 81 + lg;
    const uint4* bp = (const uint4*)w2p8 + (size_t)lg * 512 + wid * 32 + l16;
    for (int kq0 = 0; kq0 < 80; kq0 += 4) {
      U2L a[4];
      #pragma unroll
      for (int mf = 0; mf < 4; ++mf)
        a[mf].u = arow[mf * (16 * 81) + kq0];
      U4L2 q0, q1;
      const uint4* bpi = bp + (size_t)kq0 * 512;
      q0.u = bpi[0];
      q1.u = bpi[16];
      long long bbl[4] = {q0.l[0], q0.l[1], q1.l[0], q1.l[1]};
      #pragma unroll
      for (int nf = 0; nf < 4; ++nf)
        #pragma unroll
        for (int mf = 0; mf < 4; ++mf)
          acc[mf][nf] = __builtin_amdgcn_mfma_f32_16x16x32_fp8_fp8(
              a[mf].l, bbl[nf], acc[mf][nf], 0, 0, 0);
    }
  }

  // ---- phase 3: fold b2 (permuted cols), log_softmax, nt f32x4 store ----
  {
    f32x4 b2v = *(const f32x4*)&b2[wid * 64 + l16 * 4];
    #pragma unroll
    for (int mf = 0; mf < 4; ++mf)
      #pragma unroll
      for (int nf = 0; nf < 4; ++nf)
        #pragma unroll
        for (int r = 0; r < 4; ++r)
          acc[mf][nf][r] += b2v[nf];
  }

  #pragma unroll
  for (int mf = 0; mf < 4; ++mf)
    #pragma unroll
    for (int r = 0; r < 4; ++r) {
      float pm = -3.4e38f;
      #pragma unroll
      for (int nf = 0; nf < 4; ++nf) pm = fmaxf(pm, acc[mf][nf][r]);
      pm = fmaxf(pm, __shfl_xor(pm, 1));
      pm = fmaxf(pm, __shfl_xor(pm, 2));
      pm = fmaxf(pm, __shfl_xor(pm, 4));
      pm = fmaxf(pm, __shfl_xor(pm, 8));
      float s = 0.f;
      #pragma unroll
      for (int nf = 0; nf < 4; ++nf) s += __expf(acc[mf][nf][r] - pm);
      s += __shfl_xor(s, 1);
      s += __shfl_xor(s, 2);
      s += __shfl_xor(s, 4);
      s += __shfl_xor(s, 8);
      if (l16 == 0) {
        int row = mf * 16 + lg * 4 + r;
        red[wid][row][0] = pm;
        red[wid][row][1] = s;
      }
    }
  __syncthreads();

  if (tid < 64) {
    float M = -3.4e38f;
    #pragma unroll
    for (int w16 = 0; w16 < 16; ++w16) M = fmaxf(M, red[w16][tid][0]);
    float S = 0.f;
    #pragma unroll
    for (int w16 = 0; w16 < 16; ++w16)
      S += red[w16][tid][1] * __expf(red[w16][tid][0] - M);
    lzs[tid] = M + __logf(S);
  }
  __syncthreads();

  float* outb = out + (size_t)(b * T_ + t) * U_ * V_;
  #pragma unroll
  for (int mf = 0; mf < 4; ++mf)
    #pragma unroll
    for (int r = 0; r < 4; ++r) {
      int row = mf * 16 + lg * 4 + r;
      float lz = lzs[row];
      f32x4 o;
      o[0] = acc[mf][0][r] - lz;
      o[1] = acc[mf][1][r] - lz;
      o[2] = acc[mf][2][r] - lz;
      o[3] = acc[mf][3][r] - lz;
      __builtin_nontemporal_store(
          o, (f32x4*)&outb[(size_t)row * V_ + wid * 64 + l16 * 4]);
    }
}

extern "C" void kernel_launch(void* const* d_in, const int* in_sizes, int n_in,
                              void* d_out, int out_size, void* d_ws, size_t ws_size,
                              hipStream_t stream) {
  const float* src = (const float*)d_in[0];
  const int*   slen = (const int*)d_in[1];
  const float* tgt = (const float*)d_in[2];
  const int*   tlen = (const int*)d_in[3];
  const float* W1 = (const float*)d_in[4];
  const float* b1 = (const float*)d_in[5];
  const float* W2 = (const float*)d_in[6];
  const float* b2 = (const float*)d_in[7];
  float* out = (float*)d_out;

  float* ps   = (float*)d_ws;                 // 512*640 f32
  float* pt   = ps + 512 * 640;               // 256*640 f32
  uint2* w2p8 = (uint2*)(pt + 256 * 640);     // 80*1024 uint2 (fp8 W2)
  uint2* a8   = w2p8 + 80 * 1024;             // 512*5120 uint2 (fp8 A, 21MB)

  k_prep<<<272, 640, 0, stream>>>(W2, w2p8, slen, tlen,
                                  out + (size_t)B_ * T_ * U_ * V_,
                                  src, tgt, W1, b1, ps, pt);
  k_genA<<<512, 1024, 0, stream>>>(ps, pt, a8);
  k_joint2<<<512, 1024, 0, stream>>>(a8, w2p8, b2, out);
}